// Round 15
// baseline (204.650 us; speedup 1.0000x reference)
//
#include <hip/hip_runtime.h>
#include <hip/hip_bf16.h>
#include <cstdint>
#include <cstddef>

#define DEVFN static __device__ __forceinline__

typedef __attribute__((ext_vector_type(8))) short bf16x8;
typedef __attribute__((ext_vector_type(4))) float f32x4;

static constexpr int kB = 8192;
static constexpr int kIN = 1024;
static constexpr int kH = 2048;

DEVFN unsigned short f32_to_bf16(float f) {
  union { float f; unsigned int u; } v; v.f = f;
  unsigned int x = v.u;
  x += 0x7fffu + ((x >> 16) & 1u);   // round-to-nearest-even
  return (unsigned short)(x >> 16);
}
DEVFN float bf16_to_f32(unsigned short u) {
  union { unsigned int u; float f; } v; v.u = (unsigned int)u << 16;
  return v.f;
}
DEVFN float fast_sigmoid(float x) { return 1.0f / (1.0f + __expf(-x)); }
DEVFN float fast_tanh(float x)    { return 1.0f - 2.0f / (1.0f + __expf(2.0f * x)); }

// fused cast pass: fp32 -> bf16 for x, Wx, Wh, Uz (h is cast inside GEMM1)
__global__ void cast_all(const float* __restrict__ x, const float* __restrict__ Wx,
                         const float* __restrict__ Wh, const float* __restrict__ Uz,
                         unsigned short* __restrict__ xb, unsigned short* __restrict__ Wxb,
                         unsigned short* __restrict__ Wcat) {
  const long i = (long)blockIdx.x * blockDim.x + threadIdx.x;  // vec4 index
  const float* src; unsigned short* dst; int sh, stride, off; long li;
  if (i < 2097152L)      { li = i;            src = x;  dst = xb;   sh = 8; stride = 1024; off = 0; }
  else if (i < 2621440L) { li = i - 2097152L; src = Wx; dst = Wxb;  sh = 8; stride = 1024; off = 0; }
  else if (i < 3670016L) { li = i - 2621440L; src = Wh; dst = Wcat; sh = 9; stride = 4096; off = 0; }
  else                   { li = i - 3670016L; src = Uz; dst = Wcat; sh = 9; stride = 4096; off = 2048; }
  float4 v = *(const float4*)(src + li * 4);
  const long row = li >> sh;
  const long col = (li & ((1L << sh) - 1)) * 4;
  unsigned short* d = dst + row * stride + off + col;
  ushort4 o;
  o.x = f32_to_bf16(v.x); o.y = f32_to_bf16(v.y);
  o.z = f32_to_bf16(v.z); o.w = f32_to_bf16(v.w);
  *(ushort4*)d = o;
}

typedef const __attribute__((address_space(1))) unsigned int* gptr_t;
typedef __attribute__((address_space(3))) unsigned int* lptr_t;
DEVFN void gload16(const unsigned short* g, unsigned short* l) {
  __builtin_amdgcn_global_load_lds((gptr_t)g, (lptr_t)l, 16, 0, 0);
}

DEVFN void bar() { __builtin_amdgcn_s_barrier(); }
#define VMC0()  asm volatile("s_waitcnt vmcnt(0)" ::: "memory")
#define VMC2()  asm volatile("s_waitcnt vmcnt(2)" ::: "memory")
#define VMC10() asm volatile("s_waitcnt vmcnt(10)" ::: "memory")

// LDS geometry: 8 regions of [128 rows][64 bf16] (16 KiB each) = 128 KiB.
// region = buf*4 + op*2 + half   (op: 0=A, 1=B; half: rows 0-127 / 128-255)
// Swizzle (T2): element col stored at  c ^ ((row&7)*8).
// global_load_lds writes LINEAR; global SOURCE col is pre-swizzled (rule 21).
//
// ONE-PHASE-AHEAD fragment pipeline (best-measured structure, r7/r12/r13):
//   Stage plan: ph1=A1h1(2j+1), ph3=B0'h0, ph4=B0'h1, ph5=A0'h0, ph6=A0'h1,
//   ph7=B1'h0, ph8=B1'h1+A1'h0   (buf0'=2j+2, buf1'=2j+3)
//   Drains: vmcnt@ph3 (retires buf1') and vmcnt(2)@ph7 (retires buf0').
//
// GEMM1-only fused h-cast (EPI==0): 4 float4 loads at ph1 start, convert +
// 2x16B store in ph2; ph3 drain becomes vmcnt(10).
//
// BOTH epilogues drain (VMC0+bar: each wave drains its own outstanding
// gload_lds before the barrier) then reuse L as a 256x256 bf16 repack
// buffer Z for fully-coalesced global I/O.

template<int BUF, int QM>
DEVFN void ldA(bf16x8 (&a)[4][2], const unsigned short* lds, int wm, int lr, int lg) {
  const unsigned short* rg = lds + (size_t)(BUF * 4 + wm) * 8192;
#pragma unroll
  for (int mi = 0; mi < 4; ++mi) {
    const int rl = QM * 64 + mi * 16 + lr;
#pragma unroll
    for (int kk = 0; kk < 2; ++kk) {
      const int kel = (kk * 32 + lg * 8) ^ ((rl & 7) * 8);
      a[mi][kk] = *(const bf16x8*)(rg + rl * 64 + kel);
    }
  }
}

template<int BUF, int QN>
DEVFN void ldB(bf16x8 (&b)[4][2], const unsigned short* lds, int wn, int lr, int lg) {
  const unsigned short* rg = lds + (size_t)(BUF * 4 + 2 + (wn >> 1)) * 8192;
#pragma unroll
  for (int ni = 0; ni < 2; ++ni) {
    const int n = QN * 2 + ni;
    const int cl = (wn & 1) * 64 + n * 16 + lr;
#pragma unroll
    for (int kk = 0; kk < 2; ++kk) {
      const int kel = (kk * 32 + lg * 8) ^ ((cl & 7) * 8);
      b[n][kk] = *(const bf16x8*)(rg + cl * 64 + kel);
    }
  }
}

template<int QM, int QN>
DEVFN void mfmaQ(f32x4 (&acc)[8][4], bf16x8 (&a)[4][2], bf16x8 (&b)[4][2]) {
  __builtin_amdgcn_s_setprio(1);
#pragma unroll
  for (int mi = 0; mi < 4; ++mi)
#pragma unroll
    for (int ni = 0; ni < 2; ++ni)
#pragma unroll
      for (int kk = 0; kk < 2; ++kk)
        acc[QM * 4 + mi][QN * 2 + ni] = __builtin_amdgcn_mfma_f32_16x16x32_bf16(
            a[mi][kk], b[QN * 2 + ni][kk], acc[QM * 4 + mi][QN * 2 + ni], 0, 0, 0);
  __builtin_amdgcn_s_setprio(0);
}

// C = A (MxK) * W^T (W NxK); bias per col.
//  EPI==0: zOut = bf16(tanh(.)) via LDS-repack; also casts h slice (hSrc->hDst)
//  EPI==1: u = sigmoid(.); out = u*h + (1-u)*z, h/z bf16 from hzBuf; repack epi
template<int EPI>
__global__ __launch_bounds__(512, 1)
void gemm256(const unsigned short* __restrict__ A,
             const unsigned short* __restrict__ W,
             const float* __restrict__ bias,
             int M, int K,
             unsigned short* __restrict__ zOut,
             const unsigned short* __restrict__ hzBuf, int ldhz,
             float* __restrict__ out, int ldo,
             const float* __restrict__ hSrc,
             unsigned short* __restrict__ hDst)
{
  __shared__ unsigned short lds[8][8192];
  unsigned short* L = &lds[0][0];

  const int nTM = M >> 8;
  const int bm = blockIdx.x % nTM, bn = blockIdx.x / nTM;
  const int rowBase = bm << 8, colBase = bn << 8;

  const int t = threadIdx.x;
  const int l = t & 63;
  const int w = t >> 6;
  const int lr = l & 15, lg = l >> 4;
  const int wm = w >> 2, wn = w & 3;

  // staging addresses: thread t covers lds elems [t*8, t*8+8) of each 8KB slab
  const int srow = t >> 3;                       // 0..63
  const int scol = (t & 7) * 8;                  // 0..56
  const int kcSrc = scol ^ ((srow & 7) * 8);     // inverse-swizzled source col
  const unsigned short* gA = A + (size_t)(rowBase + srow) * K + kcSrc;
  const unsigned short* gB = W + (size_t)(colBase + srow) * K + kcSrc;

  // fused h-cast addressing (EPI==0)
  const int hr0 = rowBase + (t >> 4);
  const int hcol = colBase + (t & 15) * 16;
  const float* hp = (EPI == 0) ? hSrc + (size_t)hr0 * 2048 + hcol : nullptr;
  unsigned short* hq = (EPI == 0) ? hDst + (size_t)hr0 * 4096 + hcol : nullptr;

#define STAGE(BUF, OP, HALF, KT) do {                                          \
    const unsigned short* gs = ((OP) ? gB : gA)                                \
        + (size_t)((HALF) * 128) * K + (size_t)(KT) * 64;                      \
    unsigned short* ld = L + (size_t)((BUF) * 4 + (OP) * 2 + (HALF)) * 8192    \
        + w * 512;                                                             \
    gload16(gs, ld);                                                           \
    gload16(gs + (size_t)64 * K, ld + 4096);                                   \
  } while (0)

  f32x4 acc[8][4] = {};
  bf16x8 a[4][2], b[4][2];

  // prologue
  STAGE(0, 1, 0, 0); STAGE(0, 1, 1, 0); STAGE(0, 0, 0, 0); STAGE(0, 0, 1, 0);
  STAGE(1, 1, 0, 1); STAGE(1, 1, 1, 1); STAGE(1, 0, 0, 1); STAGE(1, 0, 1, 1);
  VMC0();
  bar();
  ldA<0, 0>(a, L, wm, lr, lg);
  ldB<0, 0>(b, L, wn, lr, lg);

  const int NP = K >> 7;   // pairs of BK=64 K-tiles
  for (int j = 0; j < NP; ++j) {
    const bool more = (j + 1 < NP);
    const int ktb1 = 2 * j + 1;
    const int kt0n = more ? 2 * j + 2 : 2 * j;      // clamped: benign restage
    const int kt1n = more ? 2 * j + 3 : 2 * j + 1;

    // ph1: Q00-b0.  [EPI0: h-cast loads first]  pre: B1b0 -> b23.  stage A1h1.
    float4 v0, v1, v2, v3;
    if (EPI == 0) {
      v0 = *(const float4*)(hp);
      v1 = *(const float4*)(hp + 4);
      v2 = *(const float4*)(hp + 8);
      v3 = *(const float4*)(hp + 12);
    }
    ldB<0, 1>(b, L, wn, lr, lg);
    STAGE(1, 0, 1, ktb1);
    bar();
    mfmaQ<0, 0>(acc, a, b);
    bar();
    // ph2: Q01-b0.  post: a <- A1b0.  [EPI0: convert + store h slice]
    bar();
    mfmaQ<0, 1>(acc, a, b);
    ldA<0, 1>(a, L, wm, lr, lg);
    if (EPI == 0) {
      bf16x8 q0, q1;
      q0[0] = (short)f32_to_bf16(v0.x); q0[1] = (short)f32_to_bf16(v0.y);
      q0[2] = (short)f32_to_bf16(v0.z); q0[3] = (short)f32_to_bf16(v0.w);
      q0[4] = (short)f32_to_bf16(v1.x); q0[5] = (short)f32_to_bf16(v1.y);
      q0[6] = (short)f32_to_bf16(v1.z); q0[7] = (short)f32_to_bf16(v1.w);
      q1[0] = (short)f32_to_bf16(v2.x); q1[1] = (short)f32_to_bf16(v2.y);
      q1[2] = (short)f32_to_bf16(v2.z); q1[3] = (short)f32_to_bf16(v2.w);
      q1[4] = (short)f32_to_bf16(v3.x); q1[5] = (short)f32_to_bf16(v3.y);
      q1[6] = (short)f32_to_bf16(v3.z); q1[7] = (short)f32_to_bf16(v3.w);
      *(bf16x8*)(hq) = q0;
      *(bf16x8*)(hq + 8) = q1;
      hp += 32 * 2048;
      hq += 32 * 4096;
    }
    bar();
    // ph3: Q10-b0.  stage B0'h0.  drain buf1' (EPI0: vmcnt(10), EPI1: vmcnt(2)).
    STAGE(0, 1, 0, kt0n);
    bar();
    mfmaQ<1, 0>(acc, a, b);
    if (EPI == 0) { VMC10(); } else { VMC2(); }
    bar();
    // ph4: Q11-b0.  pre: B0b1 -> b01.  stage B0'h1.  post: aLo <- A0b1.
    ldB<1, 0>(b, L, wn, lr, lg);
    STAGE(0, 1, 1, kt0n);
    bar();
    mfmaQ<1, 1>(acc, a, b);
    ldA<1, 0>(a, L, wm, lr, lg);
    bar();
    // ph5: Q00-b1.  pre: B1b1 -> b23.  stage A0'h0.
    ldB<1, 1>(b, L, wn, lr, lg);
    STAGE(0, 0, 0, kt0n);
    bar();
    mfmaQ<0, 0>(acc, a, b);
    bar();
    // ph6: Q01-b1.  stage A0'h1.  post: a <- A1b1.
    STAGE(0, 0, 1, kt0n);
    bar();
    mfmaQ<0, 1>(acc, a, b);
    ldA<1, 1>(a, L, wm, lr, lg);
    bar();
    // ph7: Q10-b1.  stage B1'h0.  drain buf0' = vmcnt(2).
    STAGE(1, 1, 0, kt1n);
    bar();
    mfmaQ<1, 0>(acc, a, b);
    VMC2();
    bar();
    // ph8: Q11-b1.  pre: B0 next -> b01.  stage B1'h1 + A1'h0.  post: a <- A0 next.
    ldB<0, 0>(b, L, wn, lr, lg);
    STAGE(1, 1, 1, kt1n);
    STAGE(1, 0, 0, kt1n);
    bar();
    mfmaQ<1, 1>(acc, a, b);
    ldA<0, 0>(a, L, wm, lr, lg);
    bar();
  }
#undef STAGE

  // ---- epilogues: drain own outstanding gload_lds, then repack via L ----
  VMC0();
  bar();
  unsigned short* Z = L;   // 256x256 bf16 = 128 KiB exactly

  // phase A: acc -> Z (swizzled bf16).  EPI0 stores tanh(pre); EPI1 stores pre.
#pragma unroll
  for (int m = 0; m < 8; ++m) {
    const int rl = wm * 128 + m * 16 + lg * 4;
#pragma unroll
    for (int n = 0; n < 4; ++n) {
      const int cl = wn * 64 + n * 16 + lr;
      const float bs = bias[colBase + cl];
#pragma unroll
      for (int q = 0; q < 4; ++q) {
        const int r = rl + q;
        const int sc = cl ^ ((r & 7) * 8);
        const float pre = acc[m][n][q] + bs;
        Z[r * 256 + sc] = f32_to_bf16(EPI == 0 ? fast_tanh(pre) : pre);
      }
    }
  }
  bar();

  // phase B: 16 iterations; 32 consecutive lanes = one 512B tile-row segment.
#pragma unroll
  for (int s = 0; s < 16; ++s) {
    const int gofs = (s * 512 + t) * 8;
    const int row = gofs >> 8;
    const int c0 = gofs & 255;
    const int sc0 = c0 ^ ((row & 7) * 8);
    bf16x8 v = *(const bf16x8*)(Z + row * 256 + sc0);
    if (EPI == 0) {
      *(bf16x8*)(zOut + (size_t)(rowBase + row) * ldhz + colBase + c0) = v;
    } else {
      const size_t hzo = (size_t)(rowBase + row) * ldhz + colBase + c0;
      bf16x8 hv = *(const bf16x8*)(hzBuf + hzo);           // h slice
      bf16x8 zv = *(const bf16x8*)(hzBuf + hzo + 2048);    // z slice
      float o[8];
#pragma unroll
      for (int e = 0; e < 8; ++e) {
        const float u = fast_sigmoid(bf16_to_f32((unsigned short)v[e]));
        o[e] = u * bf16_to_f32((unsigned short)hv[e])
             + (1.0f - u) * bf16_to_f32((unsigned short)zv[e]);
      }
      float* op = out + (size_t)(rowBase + row) * ldo + colBase + c0;
      *(float4*)(op)     = make_float4(o[0], o[1], o[2], o[3]);
      *(float4*)(op + 4) = make_float4(o[4], o[5], o[6], o[7]);
    }
  }
}

extern "C" void kernel_launch(void* const* d_in, const int* in_sizes, int n_in,
                              void* d_out, int out_size, void* d_ws, size_t ws_size,
                              hipStream_t stream) {
  const float* h  = (const float*)d_in[0];   // (B,H)
  const float* x  = (const float*)d_in[1];   // (B,IN)
  const float* Wx = (const float*)d_in[2];   // (H,IN)
  const float* bx = (const float*)d_in[3];   // (H)
  const float* Wh = (const float*)d_in[4];   // (H,H)
  const float* Uz = (const float*)d_in[5];   // (H,H)
  const float* bu = (const float*)d_in[6];   // (H)
  float* out = (float*)d_out;

  unsigned short* ws   = (unsigned short*)d_ws;
  unsigned short* xb   = ws;                          // B*IN
  unsigned short* Wxb  = xb + (size_t)kB * kIN;       // H*IN
  unsigned short* Wcat = Wxb + (size_t)kH * kIN;      // H*2H  ([Wh|Uz])
  unsigned short* Acat = Wcat + (size_t)kH * 2 * kH;  // B*2H  ([h|z])

  // x, Wx, Wh, Uz casts: 4,718,592 vec4 units / 256 = 18432 blocks
  cast_all<<<18432, 256, 0, stream>>>(x, Wx, Wh, Uz, xb, Wxb, Wcat);

  const int grid = (kB / 256) * (kH / 256);  // 32 * 8 = 256 = 1 block/CU

  // GEMM1: z = tanh(x Wx^T + bx) -> bf16 into Acat[:, H:2H];
  //        also casts h (fp32) -> Acat[:, 0:H] fused into the K-loop.
  gemm256<0><<<grid, 512, 0, stream>>>(
      xb, Wxb, bx, kB, kIN, Acat + kH, nullptr, 2 * kH, nullptr, 0, h, Acat);

  // GEMM2: u = sigmoid([h|z] [Wh|Uz]^T + bu); out = u*h + (1-u)*z (h,z bf16)
  gemm256<1><<<grid, 512, 0, stream>>>(
      Acat, Wcat, bu, kB, 2 * kH, nullptr, Acat, 2 * kH, out, kH, nullptr, nullptr);
}

// Round 16
// 204.153 us; speedup vs baseline: 1.0024x; 1.0024x over previous
//
#include <hip/hip_runtime.h>
#include <hip/hip_bf16.h>
#include <cstdint>
#include <cstddef>

#define DEVFN static __device__ __forceinline__

typedef __attribute__((ext_vector_type(8))) short bf16x8;
typedef __attribute__((ext_vector_type(4))) float f32x4;

static constexpr int kB = 8192;
static constexpr int kIN = 1024;
static constexpr int kH = 2048;

DEVFN unsigned short f32_to_bf16(float f) {
  union { float f; unsigned int u; } v; v.f = f;
  unsigned int x = v.u;
  x += 0x7fffu + ((x >> 16) & 1u);   // round-to-nearest-even
  return (unsigned short)(x >> 16);
}
DEVFN float bf16_to_f32(unsigned short u) {
  union { unsigned int u; float f; } v; v.u = (unsigned int)u << 16;
  return v.f;
}
DEVFN float fast_sigmoid(float x) { return 1.0f / (1.0f + __expf(-x)); }
DEVFN float fast_tanh(float x)    { return 1.0f - 2.0f / (1.0f + __expf(2.0f * x)); }

// fused cast pass: fp32 -> bf16 for x, Wx, Wh, Uz (h is cast inside GEMM1)
__global__ void cast_all(const float* __restrict__ x, const float* __restrict__ Wx,
                         const float* __restrict__ Wh, const float* __restrict__ Uz,
                         unsigned short* __restrict__ xb, unsigned short* __restrict__ Wxb,
                         unsigned short* __restrict__ Wcat) {
  const long i = (long)blockIdx.x * blockDim.x + threadIdx.x;  // vec4 index
  const float* src; unsigned short* dst; int sh, stride, off; long li;
  if (i < 2097152L)      { li = i;            src = x;  dst = xb;   sh = 8; stride = 1024; off = 0; }
  else if (i < 2621440L) { li = i - 2097152L; src = Wx; dst = Wxb;  sh = 8; stride = 1024; off = 0; }
  else if (i < 3670016L) { li = i - 2621440L; src = Wh; dst = Wcat; sh = 9; stride = 4096; off = 0; }
  else                   { li = i - 3670016L; src = Uz; dst = Wcat; sh = 9; stride = 4096; off = 2048; }
  float4 v = *(const float4*)(src + li * 4);
  const long row = li >> sh;
  const long col = (li & ((1L << sh) - 1)) * 4;
  unsigned short* d = dst + row * stride + off + col;
  ushort4 o;
  o.x = f32_to_bf16(v.x); o.y = f32_to_bf16(v.y);
  o.z = f32_to_bf16(v.z); o.w = f32_to_bf16(v.w);
  *(ushort4*)d = o;
}

typedef const __attribute__((address_space(1))) unsigned int* gptr_t;
typedef __attribute__((address_space(3))) unsigned int* lptr_t;
DEVFN void gload16(const unsigned short* g, unsigned short* l) {
  __builtin_amdgcn_global_load_lds((gptr_t)g, (lptr_t)l, 16, 0, 0);
}

DEVFN void bar() { __builtin_amdgcn_s_barrier(); }
#define VMC0()  asm volatile("s_waitcnt vmcnt(0)" ::: "memory")
#define VMC2()  asm volatile("s_waitcnt vmcnt(2)" ::: "memory")
#define VMC10() asm volatile("s_waitcnt vmcnt(10)" ::: "memory")

// LDS geometry: 8 regions of [128 rows][64 bf16] (16 KiB each) = 128 KiB.
// region = buf*4 + op*2 + half   (op: 0=A, 1=B; half: rows 0-127 / 128-255)
// Swizzle (T2): element col stored at  c ^ ((row&7)*8).
// global_load_lds writes LINEAR; global SOURCE col is pre-swizzled (rule 21).
//
// ONE-PHASE-AHEAD fragment pipeline (best-measured structure, r7/r12/r13):
//   Stage plan: ph1=A1h1(2j+1), ph3=B0'h0, ph4=B0'h1, ph5=A0'h0, ph6=A0'h1,
//   ph7=B1'h0, ph8=B1'h1+A1'h0   (buf0'=2j+2, buf1'=2j+3)
//   Drains: vmcnt@ph3 (retires buf1') and vmcnt(2)@ph7 (retires buf0').
//
// GEMM1-only fused h-cast (EPI==0): 4 float4 loads at ph1 start, convert +
// 2x16B store in ph2; ph3 drain becomes vmcnt(10).

template<int BUF, int QM>
DEVFN void ldA(bf16x8 (&a)[4][2], const unsigned short* lds, int wm, int lr, int lg) {
  const unsigned short* rg = lds + (size_t)(BUF * 4 + wm) * 8192;
#pragma unroll
  for (int mi = 0; mi < 4; ++mi) {
    const int rl = QM * 64 + mi * 16 + lr;
#pragma unroll
    for (int kk = 0; kk < 2; ++kk) {
      const int kel = (kk * 32 + lg * 8) ^ ((rl & 7) * 8);
      a[mi][kk] = *(const bf16x8*)(rg + rl * 64 + kel);
    }
  }
}

template<int BUF, int QN>
DEVFN void ldB(bf16x8 (&b)[4][2], const unsigned short* lds, int wn, int lr, int lg) {
  const unsigned short* rg = lds + (size_t)(BUF * 4 + 2 + (wn >> 1)) * 8192;
#pragma unroll
  for (int ni = 0; ni < 2; ++ni) {
    const int n = QN * 2 + ni;
    const int cl = (wn & 1) * 64 + n * 16 + lr;
#pragma unroll
    for (int kk = 0; kk < 2; ++kk) {
      const int kel = (kk * 32 + lg * 8) ^ ((cl & 7) * 8);
      b[n][kk] = *(const bf16x8*)(rg + cl * 64 + kel);
    }
  }
}

template<int QM, int QN>
DEVFN void mfmaQ(f32x4 (&acc)[8][4], bf16x8 (&a)[4][2], bf16x8 (&b)[4][2]) {
  __builtin_amdgcn_s_setprio(1);
#pragma unroll
  for (int mi = 0; mi < 4; ++mi)
#pragma unroll
    for (int ni = 0; ni < 2; ++ni)
#pragma unroll
      for (int kk = 0; kk < 2; ++kk)
        acc[QM * 4 + mi][QN * 2 + ni] = __builtin_amdgcn_mfma_f32_16x16x32_bf16(
            a[mi][kk], b[QN * 2 + ni][kk], acc[QM * 4 + mi][QN * 2 + ni], 0, 0, 0);
  __builtin_amdgcn_s_setprio(0);
}

// C = A (MxK) * W^T (W NxK); bias per col.
//  EPI==0: zOut = bf16(tanh(.)) via LDS-repack; also casts h slice (hSrc->hDst)
//  EPI==1: u = sigmoid(.); out = u*h + (1-u)*z, h/z read bf16 from hzBuf
template<int EPI>
__global__ __launch_bounds__(512, 1)
void gemm256(const unsigned short* __restrict__ A,
             const unsigned short* __restrict__ W,
             const float* __restrict__ bias,
             int M, int K,
             unsigned short* __restrict__ zOut,
             const unsigned short* __restrict__ hzBuf, int ldhz,
             float* __restrict__ out, int ldo,
             const float* __restrict__ hSrc,
             unsigned short* __restrict__ hDst)
{
  __shared__ unsigned short lds[8][8192];
  unsigned short* L = &lds[0][0];

  const int nTM = M >> 8;
  const int bm = blockIdx.x % nTM, bn = blockIdx.x / nTM;
  const int rowBase = bm << 8, colBase = bn << 8;

  const int t = threadIdx.x;
  const int l = t & 63;
  const int w = t >> 6;
  const int lr = l & 15, lg = l >> 4;
  const int wm = w >> 2, wn = w & 3;

  // staging addresses: thread t covers lds elems [t*8, t*8+8) of each 8KB slab
  const int srow = t >> 3;                       // 0..63
  const int scol = (t & 7) * 8;                  // 0..56
  const int kcSrc = scol ^ ((srow & 7) * 8);     // inverse-swizzled source col
  const unsigned short* gA = A + (size_t)(rowBase + srow) * K + kcSrc;
  const unsigned short* gB = W + (size_t)(colBase + srow) * K + kcSrc;

  // fused h-cast addressing (EPI==0): thread t -> row rowBase+j*32+(t>>4),
  // cols colBase+(t&15)*16 .. +16  (16 lanes x 64B = coalesced 1KB)
  const int hr0 = rowBase + (t >> 4);
  const int hcol = colBase + (t & 15) * 16;
  const float* hp = (EPI == 0) ? hSrc + (size_t)hr0 * 2048 + hcol : nullptr;
  unsigned short* hq = (EPI == 0) ? hDst + (size_t)hr0 * 4096 + hcol : nullptr;

#define STAGE(BUF, OP, HALF, KT) do {                                          \
    const unsigned short* gs = ((OP) ? gB : gA)                                \
        + (size_t)((HALF) * 128) * K + (size_t)(KT) * 64;                      \
    unsigned short* ld = L + (size_t)((BUF) * 4 + (OP) * 2 + (HALF)) * 8192    \
        + w * 512;                                                             \
    gload16(gs, ld);                                                           \
    gload16(gs + (size_t)64 * K, ld + 4096);                                   \
  } while (0)

  f32x4 acc[8][4] = {};
  bf16x8 a[4][2], b[4][2];

  // prologue: stage buf0=tile0, buf1=tile1 fully; drain; preload a=A0b0, b01=B0b0
  STAGE(0, 1, 0, 0); STAGE(0, 1, 1, 0); STAGE(0, 0, 0, 0); STAGE(0, 0, 1, 0);
  STAGE(1, 1, 0, 1); STAGE(1, 1, 1, 1); STAGE(1, 0, 0, 1); STAGE(1, 0, 1, 1);
  VMC0();
  bar();
  ldA<0, 0>(a, L, wm, lr, lg);
  ldB<0, 0>(b, L, wn, lr, lg);

  const int NP = K >> 7;   // pairs of BK=64 K-tiles
  for (int j = 0; j < NP; ++j) {
    const bool more = (j + 1 < NP);
    const int ktb1 = 2 * j + 1;
    const int kt0n = more ? 2 * j + 2 : 2 * j;      // clamped: benign restage
    const int kt1n = more ? 2 * j + 3 : 2 * j + 1;

    // ph1: Q00-b0.  [EPI0: issue h-cast loads FIRST so later wait is counted]
    //      pre: B1b0 -> b23.  stage A1h1.
    float4 v0, v1, v2, v3;
    if (EPI == 0) {
      v0 = *(const float4*)(hp);
      v1 = *(const float4*)(hp + 4);
      v2 = *(const float4*)(hp + 8);
      v3 = *(const float4*)(hp + 12);
    }
    ldB<0, 1>(b, L, wn, lr, lg);
    STAGE(1, 0, 1, ktb1);
    bar();
    mfmaQ<0, 0>(acc, a, b);
    bar();
    // ph2: Q01-b0.  post: a <- A1b0.  [EPI0: convert + store h slice]
    bar();
    mfmaQ<0, 1>(acc, a, b);
    ldA<0, 1>(a, L, wm, lr, lg);
    if (EPI == 0) {
      bf16x8 q0, q1;
      q0[0] = (short)f32_to_bf16(v0.x); q0[1] = (short)f32_to_bf16(v0.y);
      q0[2] = (short)f32_to_bf16(v0.z); q0[3] = (short)f32_to_bf16(v0.w);
      q0[4] = (short)f32_to_bf16(v1.x); q0[5] = (short)f32_to_bf16(v1.y);
      q0[6] = (short)f32_to_bf16(v1.z); q0[7] = (short)f32_to_bf16(v1.w);
      q1[0] = (short)f32_to_bf16(v2.x); q1[1] = (short)f32_to_bf16(v2.y);
      q1[2] = (short)f32_to_bf16(v2.z); q1[3] = (short)f32_to_bf16(v2.w);
      q1[4] = (short)f32_to_bf16(v3.x); q1[5] = (short)f32_to_bf16(v3.y);
      q1[6] = (short)f32_to_bf16(v3.z); q1[7] = (short)f32_to_bf16(v3.w);
      *(bf16x8*)(hq) = q0;
      *(bf16x8*)(hq + 8) = q1;
      hp += 32 * 2048;
      hq += 32 * 4096;
    }
    bar();
    // ph3: Q10-b0.  stage B0'h0.  drain buf1' (EPI0: vmcnt(10), EPI1: vmcnt(2)).
    STAGE(0, 1, 0, kt0n);
    bar();
    mfmaQ<1, 0>(acc, a, b);
    if (EPI == 0) { VMC10(); } else { VMC2(); }
    bar();
    // ph4: Q11-b0.  pre: B0b1 -> b01.  stage B0'h1.  post: aLo <- A0b1.
    ldB<1, 0>(b, L, wn, lr, lg);
    STAGE(0, 1, 1, kt0n);
    bar();
    mfmaQ<1, 1>(acc, a, b);
    ldA<1, 0>(a, L, wm, lr, lg);
    bar();
    // ph5: Q00-b1.  pre: B1b1 -> b23.  stage A0'h0.
    ldB<1, 1>(b, L, wn, lr, lg);
    STAGE(0, 0, 0, kt0n);
    bar();
    mfmaQ<0, 0>(acc, a, b);
    bar();
    // ph6: Q01-b1.  stage A0'h1.  post: a <- A1b1.
    STAGE(0, 0, 1, kt0n);
    bar();
    mfmaQ<0, 1>(acc, a, b);
    ldA<1, 1>(a, L, wm, lr, lg);
    bar();
    // ph7: Q10-b1.  stage B1'h0.  drain buf0' (ph3..ph6) = vmcnt(2)
    //      (also retires this pair's cast loads/stores, ages >=4 phases).
    STAGE(1, 1, 0, kt1n);
    bar();
    mfmaQ<1, 0>(acc, a, b);
    VMC2();
    bar();
    // ph8: Q11-b1.  pre: B0 next pair -> b01.  stage B1'h1 + A1'h0.  post: a <- A0 next.
    ldB<0, 0>(b, L, wn, lr, lg);
    STAGE(1, 1, 1, kt1n);
    STAGE(1, 0, 0, kt1n);
    bar();
    mfmaQ<1, 1>(acc, a, b);
    ldA<0, 0>(a, L, wm, lr, lg);
    bar();
  }
#undef STAGE

  if (EPI == 0) {
    // ---- GEMM1 epilogue: fast tanh + LDS-repack -> coalesced 512B stores ----
    // Drain outstanding gload_lds writes into staging regions Z reuses.
    VMC0();
    bar();
    unsigned short* Z = L;   // 256x256 bf16 = 128 KiB exactly
#pragma unroll
    for (int m = 0; m < 8; ++m) {
      const int rl = wm * 128 + m * 16 + lg * 4;
#pragma unroll
      for (int n = 0; n < 4; ++n) {
        const int cl = wn * 64 + n * 16 + lr;
        const float bs = bias[colBase + cl];
#pragma unroll
        for (int q = 0; q < 4; ++q) {
          const int r = rl + q;
          const int sc = cl ^ ((r & 7) * 8);
          Z[r * 256 + sc] = f32_to_bf16(fast_tanh(acc[m][n][q] + bs));
        }
      }
    }
    bar();
#pragma unroll
    for (int s = 0; s < 16; ++s) {
      const int gofs = (s * 512 + t) * 8;
      const int row = gofs >> 8;
      const int c0 = gofs & 255;
      const int sc0 = c0 ^ ((row & 7) * 8);
      bf16x8 v = *(const bf16x8*)(Z + row * 256 + sc0);
      *(bf16x8*)(zOut + (size_t)(rowBase + row) * ldhz + colBase + c0) = v;
    }
  } else {
    // C/D layout: col = lane&15, row = (lane>>4)*4 + reg  [HW-verified]
#pragma unroll
    for (int m = 0; m < 8; ++m) {
      const int r0 = rowBase + wm * 128 + m * 16 + lg * 4;
#pragma unroll
      for (int n = 0; n < 4; ++n) {
        const int c = colBase + wn * 64 + n * 16 + lr;
        const float bs = bias[c];
#pragma unroll
        for (int q = 0; q < 4; ++q) {
          const int r = r0 + q;
          const float pre = acc[m][n][q] + bs;
          const float u = fast_sigmoid(pre);
          const float hv = bf16_to_f32(hzBuf[(size_t)r * ldhz + c]);
          const float zv = bf16_to_f32(hzBuf[(size_t)r * ldhz + 2048 + c]);
          out[(size_t)r * ldo + c] = u * hv + (1.0f - u) * zv;
        }
      }
    }
  }
}

extern "C" void kernel_launch(void* const* d_in, const int* in_sizes, int n_in,
                              void* d_out, int out_size, void* d_ws, size_t ws_size,
                              hipStream_t stream) {
  const float* h  = (const float*)d_in[0];   // (B,H)
  const float* x  = (const float*)d_in[1];   // (B,IN)
  const float* Wx = (const float*)d_in[2];   // (H,IN)
  const float* bx = (const float*)d_in[3];   // (H)
  const float* Wh = (const float*)d_in[4];   // (H,H)
  const float* Uz = (const float*)d_in[5];   // (H,H)
  const float* bu = (const float*)d_in[6];   // (H)
  float* out = (float*)d_out;

  unsigned short* ws   = (unsigned short*)d_ws;
  unsigned short* xb   = ws;                          // B*IN
  unsigned short* Wxb  = xb + (size_t)kB * kIN;       // H*IN
  unsigned short* Wcat = Wxb + (size_t)kH * kIN;      // H*2H  ([Wh|Uz])
  unsigned short* Acat = Wcat + (size_t)kH * 2 * kH;  // B*2H  ([h|z])

  // x, Wx, Wh, Uz casts: 4,718,592 vec4 units / 256 = 18432 blocks
  cast_all<<<18432, 256, 0, stream>>>(x, Wx, Wh, Uz, xb, Wxb, Wcat);

  const int grid = (kB / 256) * (kH / 256);  // 32 * 8 = 256 = 1 block/CU

  // GEMM1: z = tanh(x Wx^T + bx) -> bf16 into Acat[:, H:2H];
  //        also casts h (fp32) -> Acat[:, 0:H] fused into the K-loop.
  gemm256<0><<<grid, 512, 0, stream>>>(
      xb, Wxb, bx, kB, kIN, Acat + kH, nullptr, 2 * kH, nullptr, 0, h, Acat);

  // GEMM2: u = sigmoid([h|z] [Wh|Uz]^T + bu); out = u*h + (1-u)*z (h,z bf16)
  gemm256<1><<<grid, 512, 0, stream>>>(
      Acat, Wcat, bu, kB, 2 * kH, nullptr, Acat, 2 * kH, out, kH, nullptr, nullptr);
}

// Round 18
// 202.757 us; speedup vs baseline: 1.0093x; 1.0069x over previous
//
#include <hip/hip_runtime.h>
#include <hip/hip_bf16.h>
#include <cstdint>
#include <cstddef>

#define DEVFN static __device__ __forceinline__

typedef __attribute__((ext_vector_type(8))) short bf16x8;
typedef __attribute__((ext_vector_type(4))) float f32x4;

static constexpr int kB = 8192;
static constexpr int kIN = 1024;
static constexpr int kH = 2048;

DEVFN unsigned short f32_to_bf16(float f) {
  union { float f; unsigned int u; } v; v.f = f;
  unsigned int x = v.u;
  x += 0x7fffu + ((x >> 16) & 1u);   // round-to-nearest-even
  return (unsigned short)(x >> 16);
}
DEVFN float bf16_to_f32(unsigned short u) {
  union { unsigned int u; float f; } v; v.u = (unsigned int)u << 16;
  return v.f;
}
DEVFN float fast_sigmoid(float x) { return 1.0f / (1.0f + __expf(-x)); }
DEVFN float fast_tanh(float x)    { return 1.0f - 2.0f / (1.0f + __expf(2.0f * x)); }

// fused cast pass: fp32 -> bf16 for x, Wx, Wh, Uz (h is cast inside GEMM1)
__global__ void cast_all(const float* __restrict__ x, const float* __restrict__ Wx,
                         const float* __restrict__ Wh, const float* __restrict__ Uz,
                         unsigned short* __restrict__ xb, unsigned short* __restrict__ Wxb,
                         unsigned short* __restrict__ Wcat) {
  const long i = (long)blockIdx.x * blockDim.x + threadIdx.x;  // vec4 index
  const float* src; unsigned short* dst; int sh, stride, off; long li;
  if (i < 2097152L)      { li = i;            src = x;  dst = xb;   sh = 8; stride = 1024; off = 0; }
  else if (i < 2621440L) { li = i - 2097152L; src = Wx; dst = Wxb;  sh = 8; stride = 1024; off = 0; }
  else if (i < 3670016L) { li = i - 2621440L; src = Wh; dst = Wcat; sh = 9; stride = 4096; off = 0; }
  else                   { li = i - 3670016L; src = Uz; dst = Wcat; sh = 9; stride = 4096; off = 2048; }
  float4 v = *(const float4*)(src + li * 4);
  const long row = li >> sh;
  const long col = (li & ((1L << sh) - 1)) * 4;
  unsigned short* d = dst + row * stride + off + col;
  ushort4 o;
  o.x = f32_to_bf16(v.x); o.y = f32_to_bf16(v.y);
  o.z = f32_to_bf16(v.z); o.w = f32_to_bf16(v.w);
  *(ushort4*)d = o;
}

typedef const __attribute__((address_space(1))) unsigned int* gptr_t;
typedef __attribute__((address_space(3))) unsigned int* lptr_t;
DEVFN void gload16(const unsigned short* g, unsigned short* l) {
  __builtin_amdgcn_global_load_lds((gptr_t)g, (lptr_t)l, 16, 0, 0);
}

DEVFN void bar() { __builtin_amdgcn_s_barrier(); }
#define VMC0()  asm volatile("s_waitcnt vmcnt(0)" ::: "memory")
#define VMC2()  asm volatile("s_waitcnt vmcnt(2)" ::: "memory")
#define VMC10() asm volatile("s_waitcnt vmcnt(10)" ::: "memory")

// LDS geometry: 8 regions of [128 rows][64 bf16] (16 KiB each) = 128 KiB.
// region = buf*4 + op*2 + half   (op: 0=A, 1=B; half: rows 0-127 / 128-255)
// Swizzle (T2): element col stored at  c ^ ((row&7)*8).
// global_load_lds writes LINEAR; global SOURCE col is pre-swizzled (rule 21).
//
// ONE-PHASE-AHEAD fragment pipeline (best-measured structure, r7/r12/r13):
//   Stage plan: ph1=A1h1(2j+1), ph3=B0'h0, ph4=B0'h1, ph5=A0'h0, ph6=A0'h1,
//   ph7=B1'h0, ph8=B1'h1+A1'h0   (buf0'=2j+2, buf1'=2j+3)
//   Drains: vmcnt@ph3 (retires buf1') and vmcnt(2)@ph7 (retires buf0').
//
// GEMM1-only fused h-cast (EPI==0): 4 float4 loads at ph1 start, convert +
// 2x16B store in ph2; ph3 drain becomes vmcnt(10).

template<int BUF, int QM>
DEVFN void ldA(bf16x8 (&a)[4][2], const unsigned short* lds, int wm, int lr, int lg) {
  const unsigned short* rg = lds + (size_t)(BUF * 4 + wm) * 8192;
#pragma unroll
  for (int mi = 0; mi < 4; ++mi) {
    const int rl = QM * 64 + mi * 16 + lr;
#pragma unroll
    for (int kk = 0; kk < 2; ++kk) {
      const int kel = (kk * 32 + lg * 8) ^ ((rl & 7) * 8);
      a[mi][kk] = *(const bf16x8*)(rg + rl * 64 + kel);
    }
  }
}

template<int BUF, int QN>
DEVFN void ldB(bf16x8 (&b)[4][2], const unsigned short* lds, int wn, int lr, int lg) {
  const unsigned short* rg = lds + (size_t)(BUF * 4 + 2 + (wn >> 1)) * 8192;
#pragma unroll
  for (int ni = 0; ni < 2; ++ni) {
    const int n = QN * 2 + ni;
    const int cl = (wn & 1) * 64 + n * 16 + lr;
#pragma unroll
    for (int kk = 0; kk < 2; ++kk) {
      const int kel = (kk * 32 + lg * 8) ^ ((cl & 7) * 8);
      b[n][kk] = *(const bf16x8*)(rg + cl * 64 + kel);
    }
  }
}

template<int QM, int QN>
DEVFN void mfmaQ(f32x4 (&acc)[8][4], bf16x8 (&a)[4][2], bf16x8 (&b)[4][2]) {
  __builtin_amdgcn_s_setprio(1);
#pragma unroll
  for (int mi = 0; mi < 4; ++mi)
#pragma unroll
    for (int ni = 0; ni < 2; ++ni)
#pragma unroll
      for (int kk = 0; kk < 2; ++kk)
        acc[QM * 4 + mi][QN * 2 + ni] = __builtin_amdgcn_mfma_f32_16x16x32_bf16(
            a[mi][kk], b[QN * 2 + ni][kk], acc[QM * 4 + mi][QN * 2 + ni], 0, 0, 0);
  __builtin_amdgcn_s_setprio(0);
}

// C = A (MxK) * W^T (W NxK); bias per col.
//  EPI==0: zOut = bf16(tanh(.)) via LDS-repack; also casts h slice (hSrc->hDst)
//  EPI==1: u = sigmoid(.); out = u*h + (1-u)*z, h/z read bf16 from hzBuf
template<int EPI>
__global__ __launch_bounds__(512, 1)
void gemm256(const unsigned short* __restrict__ A,
             const unsigned short* __restrict__ W,
             const float* __restrict__ bias,
             int M, int K,
             unsigned short* __restrict__ zOut,
             const unsigned short* __restrict__ hzBuf, int ldhz,
             float* __restrict__ out, int ldo,
             const float* __restrict__ hSrc,
             unsigned short* __restrict__ hDst)
{
  __shared__ unsigned short lds[8][8192];
  unsigned short* L = &lds[0][0];

  const int nTM = M >> 8;
  const int bm = blockIdx.x % nTM, bn = blockIdx.x / nTM;
  const int rowBase = bm << 8, colBase = bn << 8;

  const int t = threadIdx.x;
  const int l = t & 63;
  const int w = t >> 6;
  const int lr = l & 15, lg = l >> 4;
  const int wm = w >> 2, wn = w & 3;

  // staging addresses: thread t covers lds elems [t*8, t*8+8) of each 8KB slab
  const int srow = t >> 3;                       // 0..63
  const int scol = (t & 7) * 8;                  // 0..56
  const int kcSrc = scol ^ ((srow & 7) * 8);     // inverse-swizzled source col
  const unsigned short* gA = A + (size_t)(rowBase + srow) * K + kcSrc;
  const unsigned short* gB = W + (size_t)(colBase + srow) * K + kcSrc;

  // fused h-cast addressing (EPI==0): thread t -> row rowBase+j*32+(t>>4),
  // cols colBase+(t&15)*16 .. +16  (16 lanes x 64B = coalesced 1KB)
  const int hr0 = rowBase + (t >> 4);
  const int hcol = colBase + (t & 15) * 16;
  const float* hp = (EPI == 0) ? hSrc + (size_t)hr0 * 2048 + hcol : nullptr;
  unsigned short* hq = (EPI == 0) ? hDst + (size_t)hr0 * 4096 + hcol : nullptr;

#define STAGE(BUF, OP, HALF, KT) do {                                          \
    const unsigned short* gs = ((OP) ? gB : gA)                                \
        + (size_t)((HALF) * 128) * K + (size_t)(KT) * 64;                      \
    unsigned short* ld = L + (size_t)((BUF) * 4 + (OP) * 2 + (HALF)) * 8192    \
        + w * 512;                                                             \
    gload16(gs, ld);                                                           \
    gload16(gs + (size_t)64 * K, ld + 4096);                                   \
  } while (0)

  f32x4 acc[8][4] = {};
  bf16x8 a[4][2], b[4][2];

  // prologue: stage buf0=tile0, buf1=tile1 fully; drain; preload a=A0b0, b01=B0b0
  STAGE(0, 1, 0, 0); STAGE(0, 1, 1, 0); STAGE(0, 0, 0, 0); STAGE(0, 0, 1, 0);
  STAGE(1, 1, 0, 1); STAGE(1, 1, 1, 1); STAGE(1, 0, 0, 1); STAGE(1, 0, 1, 1);
  VMC0();
  bar();
  ldA<0, 0>(a, L, wm, lr, lg);
  ldB<0, 0>(b, L, wn, lr, lg);

  const int NP = K >> 7;   // pairs of BK=64 K-tiles
  for (int j = 0; j < NP; ++j) {
    const bool more = (j + 1 < NP);
    const int ktb1 = 2 * j + 1;
    const int kt0n = more ? 2 * j + 2 : 2 * j;      // clamped: benign restage
    const int kt1n = more ? 2 * j + 3 : 2 * j + 1;

    // ph1: Q00-b0.  [EPI0: issue h-cast loads FIRST so later wait is counted]
    //      pre: B1b0 -> b23.  stage A1h1.
    float4 v0, v1, v2, v3;
    if (EPI == 0) {
      v0 = *(const float4*)(hp);
      v1 = *(const float4*)(hp + 4);
      v2 = *(const float4*)(hp + 8);
      v3 = *(const float4*)(hp + 12);
    }
    ldB<0, 1>(b, L, wn, lr, lg);
    STAGE(1, 0, 1, ktb1);
    bar();
    mfmaQ<0, 0>(acc, a, b);
    bar();
    // ph2: Q01-b0.  post: a <- A1b0.  [EPI0: convert + store h slice]
    bar();
    mfmaQ<0, 1>(acc, a, b);
    ldA<0, 1>(a, L, wm, lr, lg);
    if (EPI == 0) {
      bf16x8 q0, q1;
      q0[0] = (short)f32_to_bf16(v0.x); q0[1] = (short)f32_to_bf16(v0.y);
      q0[2] = (short)f32_to_bf16(v0.z); q0[3] = (short)f32_to_bf16(v0.w);
      q0[4] = (short)f32_to_bf16(v1.x); q0[5] = (short)f32_to_bf16(v1.y);
      q0[6] = (short)f32_to_bf16(v1.z); q0[7] = (short)f32_to_bf16(v1.w);
      q1[0] = (short)f32_to_bf16(v2.x); q1[1] = (short)f32_to_bf16(v2.y);
      q1[2] = (short)f32_to_bf16(v2.z); q1[3] = (short)f32_to_bf16(v2.w);
      q1[4] = (short)f32_to_bf16(v3.x); q1[5] = (short)f32_to_bf16(v3.y);
      q1[6] = (short)f32_to_bf16(v3.z); q1[7] = (short)f32_to_bf16(v3.w);
      *(bf16x8*)(hq) = q0;
      *(bf16x8*)(hq + 8) = q1;
      hp += 32 * 2048;
      hq += 32 * 4096;
    }
    bar();
    // ph3: Q10-b0.  stage B0'h0.  drain buf1' (EPI0: vmcnt(10), EPI1: vmcnt(2)).
    STAGE(0, 1, 0, kt0n);
    bar();
    mfmaQ<1, 0>(acc, a, b);
    if (EPI == 0) { VMC10(); } else { VMC2(); }
    bar();
    // ph4: Q11-b0.  pre: B0b1 -> b01.  stage B0'h1.  post: aLo <- A0b1.
    ldB<1, 0>(b, L, wn, lr, lg);
    STAGE(0, 1, 1, kt0n);
    bar();
    mfmaQ<1, 1>(acc, a, b);
    ldA<1, 0>(a, L, wm, lr, lg);
    bar();
    // ph5: Q00-b1.  pre: B1b1 -> b23.  stage A0'h0.
    ldB<1, 1>(b, L, wn, lr, lg);
    STAGE(0, 0, 0, kt0n);
    bar();
    mfmaQ<0, 0>(acc, a, b);
    bar();
    // ph6: Q01-b1.  stage A0'h1.  post: a <- A1b1.
    STAGE(0, 0, 1, kt0n);
    bar();
    mfmaQ<0, 1>(acc, a, b);
    ldA<1, 1>(a, L, wm, lr, lg);
    bar();
    // ph7: Q10-b1.  stage B1'h0.  drain buf0' (ph3..ph6) = vmcnt(2)
    //      (also retires this pair's cast loads/stores, ages >=4 phases).
    STAGE(1, 1, 0, kt1n);
    bar();
    mfmaQ<1, 0>(acc, a, b);
    VMC2();
    bar();
    // ph8: Q11-b1.  pre: B0 next pair -> b01.  stage B1'h1 + A1'h0.  post: a <- A0 next.
    ldB<0, 0>(b, L, wn, lr, lg);
    STAGE(1, 1, 1, kt1n);
    STAGE(1, 0, 0, kt1n);
    bar();
    mfmaQ<1, 1>(acc, a, b);
    ldA<0, 0>(a, L, wm, lr, lg);
    bar();
  }
#undef STAGE

  if (EPI == 0) {
    // ---- GEMM1 epilogue: fast tanh + LDS-repack -> coalesced 512B stores ----
    // Drain outstanding gload_lds writes into staging regions Z reuses.
    VMC0();
    bar();
    unsigned short* Z = L;   // 256x256 bf16 = 128 KiB exactly
#pragma unroll
    for (int m = 0; m < 8; ++m) {
      const int rl = wm * 128 + m * 16 + lg * 4;
#pragma unroll
      for (int n = 0; n < 4; ++n) {
        const int cl = wn * 64 + n * 16 + lr;
        const float bs = bias[colBase + cl];
#pragma unroll
        for (int q = 0; q < 4; ++q) {
          const int r = rl + q;
          const int sc = cl ^ ((r & 7) * 8);
          Z[r * 256 + sc] = f32_to_bf16(fast_tanh(acc[m][n][q] + bs));
        }
      }
    }
    bar();
#pragma unroll
    for (int s = 0; s < 16; ++s) {
      const int gofs = (s * 512 + t) * 8;
      const int row = gofs >> 8;
      const int c0 = gofs & 255;
      const int sc0 = c0 ^ ((row & 7) * 8);
      bf16x8 v = *(const bf16x8*)(Z + row * 256 + sc0);
      *(bf16x8*)(zOut + (size_t)(rowBase + row) * ldhz + colBase + c0) = v;
    }
  } else {
    // C/D layout: col = lane&15, row = (lane>>4)*4 + reg  [HW-verified]
#pragma unroll
    for (int m = 0; m < 8; ++m) {
      const int r0 = rowBase + wm * 128 + m * 16 + lg * 4;
#pragma unroll
      for (int n = 0; n < 4; ++n) {
        const int c = colBase + wn * 64 + n * 16 + lr;
        const float bs = bias[c];
#pragma unroll
        for (int q = 0; q < 4; ++q) {
          const int r = r0 + q;
          const float pre = acc[m][n][q] + bs;
          const float u = fast_sigmoid(pre);
          const float hv = bf16_to_f32(hzBuf[(size_t)r * ldhz + c]);
          const float zv = bf16_to_f32(hzBuf[(size_t)r * ldhz + 2048 + c]);
          out[(size_t)r * ldo + c] = u * hv + (1.0f - u) * zv;
        }
      }
    }
  }
}

extern "C" void kernel_launch(void* const* d_in, const int* in_sizes, int n_in,
                              void* d_out, int out_size, void* d_ws, size_t ws_size,
                              hipStream_t stream) {
  const float* h  = (const float*)d_in[0];   // (B,H)
  const float* x  = (const float*)d_in[1];   // (B,IN)
  const float* Wx = (const float*)d_in[2];   // (H,IN)
  const float* bx = (const float*)d_in[3];   // (H)
  const float* Wh = (const float*)d_in[4];   // (H,H)
  const float* Uz = (const float*)d_in[5];   // (H,H)
  const float* bu = (const float*)d_in[6];   // (H)
  float* out = (float*)d_out;

  unsigned short* ws   = (unsigned short*)d_ws;
  unsigned short* xb   = ws;                          // B*IN
  unsigned short* Wxb  = xb + (size_t)kB * kIN;       // H*IN
  unsigned short* Wcat = Wxb + (size_t)kH * kIN;      // H*2H  ([Wh|Uz])
  unsigned short* Acat = Wcat + (size_t)kH * 2 * kH;  // B*2H  ([h|z])

  // x, Wx, Wh, Uz casts: 4,718,592 vec4 units / 256 = 18432 blocks
  cast_all<<<18432, 256, 0, stream>>>(x, Wx, Wh, Uz, xb, Wxb, Wcat);

  const int grid = (kB / 256) * (kH / 256);  // 32 * 8 = 256 = 1 block/CU

  // GEMM1: z = tanh(x Wx^T + bx) -> bf16 into Acat[:, H:2H];
  //        also casts h (fp32) -> Acat[:, 0:H] fused into the K-loop.
  gemm256<0><<<grid, 512, 0, stream>>>(
      xb, Wxb, bx, kB, kIN, Acat + kH, nullptr, 2 * kH, nullptr, 0, h, Acat);

  // GEMM2: u = sigmoid([h|z] [Wh|Uz]^T + bu); out = u*h + (1-u)*z (h,z bf16)
  gemm256<1><<<grid, 512, 0, stream>>>(
      Acat, Wcat, bu, kB, 2 * kH, nullptr, Acat, 2 * kH, out, kH, nullptr, nullptr);
}